// Round 6
// baseline (203.286 us; speedup 1.0000x reference)
//
#include <hip/hip_runtime.h>
#include <math.h>

#define NEG_INF_BITS 0xFF800000u
#define SCAN_B 1024   // threads per scan block (= tile size)

typedef float f32x2_t __attribute__((ext_vector_type(2)));
typedef float f32x4_t __attribute__((ext_vector_type(4)));

__device__ __forceinline__ float2 ld_nt2(const float2* p) {
    f32x2_t v = __builtin_nontemporal_load((const f32x2_t*)p);
    return make_float2(v[0], v[1]);
}
__device__ __forceinline__ void st_nt2(float2* p, float2 v) {
    f32x2_t x = {v.x, v.y};
    __builtin_nontemporal_store(x, (f32x2_t*)p);
}

// ===========================================================================
// CSR path: zero -> hist+rank -> 3-pass scan -> scatter (no atomics) -> reduce
// ===========================================================================

__global__ void zero_counts_kernel(int* __restrict__ counts, int nseg) {
    const int i = blockIdx.x * blockDim.x + threadIdx.x;
    if (i < nseg) counts[i] = 0;
}

// A) histogram + per-row rank within segment (coalesced rank write)
__global__ void hist_rank_kernel(const int* __restrict__ inv,
                                 int* __restrict__ counts,
                                 int* __restrict__ rank, int n) {
    const int stride = gridDim.x * blockDim.x;
    const int n4 = n >> 2;
    const int4* inv4 = (const int4*)inv;
    int4* rank4 = (int4*)rank;
    for (int i = blockIdx.x * blockDim.x + threadIdx.x; i < n4; i += stride) {
        int4 s = inv4[i];
        int4 rk;
        rk.x = atomicAdd(&counts[s.x], 1);
        rk.y = atomicAdd(&counts[s.y], 1);
        rk.z = atomicAdd(&counts[s.z], 1);
        rk.w = atomicAdd(&counts[s.w], 1);
        rank4[i] = rk;
    }
    if (blockIdx.x == 0 && threadIdx.x < (n & 3)) {
        int i = (n4 << 2) + threadIdx.x;
        rank[i] = atomicAdd(&counts[inv[i]], 1);
    }
}

// B1) per-block reduce of counts tiles -> bsum[block]
__global__ __launch_bounds__(SCAN_B)
void scan_reduce_kernel(const int* __restrict__ counts,
                        int* __restrict__ bsum, int nseg) {
    __shared__ int lds[SCAN_B / 64];
    const int t = threadIdx.x;
    const int idx = blockIdx.x * SCAN_B + t;
    int v = (idx < nseg) ? counts[idx] : 0;
    for (int off = 32; off > 0; off >>= 1) v += __shfl_down(v, off, 64);
    if ((t & 63) == 0) lds[t >> 6] = v;
    __syncthreads();
    if (t < SCAN_B / 64) {
        int s = lds[t];
        for (int off = SCAN_B / 128; off > 0; off >>= 1) s += __shfl_down(s, off, 64);
        if (t == 0) bsum[blockIdx.x] = s;
    }
}

// B2) single small block: exclusive scan of bsum[nblk]; writes offsets[nseg]=total
__global__ __launch_bounds__(SCAN_B)
void scan_top_kernel(int* __restrict__ bsum, int* __restrict__ offsets,
                     int nblk, int nseg) {
    __shared__ int lds[SCAN_B];
    const int t = threadIdx.x;
    int v = (t < nblk) ? bsum[t] : 0;
    lds[t] = v;
    __syncthreads();
    for (int off = 1; off < SCAN_B; off <<= 1) {
        int x = lds[t];
        int add = (t >= off) ? lds[t - off] : 0;
        __syncthreads();
        lds[t] = x + add;
        __syncthreads();
    }
    if (t < nblk) bsum[t] = lds[t] - v;              // exclusive
    if (t == nblk - 1) offsets[nseg] = lds[t];       // total
}

// B3) per-block scan of counts tile + bsum prefix -> offsets
__global__ __launch_bounds__(SCAN_B)
void scan_down_kernel(const int* __restrict__ counts,
                      const int* __restrict__ bsum,
                      int* __restrict__ offsets, int nseg) {
    __shared__ int lds[SCAN_B];
    const int t = threadIdx.x;
    const int idx = blockIdx.x * SCAN_B + t;
    int c = (idx < nseg) ? counts[idx] : 0;
    lds[t] = c;
    __syncthreads();
    for (int off = 1; off < SCAN_B; off <<= 1) {
        int x = lds[t];
        int add = (t >= off) ? lds[t - off] : 0;
        __syncthreads();
        lds[t] = x + add;
        __syncthreads();
    }
    if (idx < nseg) offsets[idx] = bsum[blockIdx.x] + lds[t] - c;  // exclusive
}

// C) scatter row indices into CSR order — NO atomics (uses precomputed rank)
__global__ void scatteridx_kernel(const int* __restrict__ inv,
                                  const int* __restrict__ rank,
                                  const int* __restrict__ offsets,
                                  int* __restrict__ rowidx, int n) {
    const int stride = gridDim.x * blockDim.x;
    const int n4 = n >> 2;
    const int4* inv4 = (const int4*)inv;
    const int4* rank4 = (const int4*)rank;
    for (int i = blockIdx.x * blockDim.x + threadIdx.x; i < n4; i += stride) {
        int4 s  = inv4[i];
        int4 rk = rank4[i];
        int base = i << 2;
        rowidx[offsets[s.x] + rk.x] = base + 0;
        rowidx[offsets[s.y] + rk.y] = base + 1;
        rowidx[offsets[s.z] + rk.z] = base + 2;
        rowidx[offsets[s.w] + rk.w] = base + 3;
    }
    if (blockIdx.x == 0 && threadIdx.x < (n & 3)) {
        int i = (n4 << 2) + threadIdx.x;
        rowidx[offsets[inv[i]] + rank[i]] = i;
    }
}

// D) gather-reduce v2: ONE FULL WAVE per segment, float2 per lane.
//    - rowidx for the segment loaded with ONE coalesced instruction (64 lanes)
//    - row index k extracted via __shfl (no memory op)
//    - feat gathers issued in predicated unroll-16 independent batches
__global__ __launch_bounds__(256)
void seg_reduce_kernel(const float2* __restrict__ feat2,
                       const int* __restrict__ rowidx,
                       const int* __restrict__ offsets,
                       float2* __restrict__ out2,
                       int nseg,
                       const int* __restrict__ mode_p) {
    const int mode = mode_p[0];
    const int t = blockIdx.x * blockDim.x + threadIdx.x;
    const int g = t >> 6;          // segment (one 64-lane wave each)
    const int lane = t & 63;       // float2 column slot (128 cols = 64 x float2)
    if (g >= nseg) return;

    const int start = offsets[g];
    const int end   = offsets[g + 1];
    const int count = end - start;

    const bool is_max = (mode == 1);
    float2 acc = is_max ? make_float2(-INFINITY, -INFINITY) : make_float2(0.f, 0.f);

    for (int base = start; base < end; base += 64) {
        const int cnt = min(64, end - base);
        // one coalesced load: lanes 0..cnt-1 fetch the segment's row indices
        const int myrow = (lane < cnt) ? rowidx[base + lane] : 0;

        for (int kk = 0; kk < cnt; kk += 16) {
            float2 v[16];
            #pragma unroll
            for (int j = 0; j < 16; ++j) {
                if (kk + j < cnt) {
                    const int row = __shfl(myrow, kk + j, 64);
                    v[j] = ld_nt2(feat2 + (size_t)row * 64 + lane);
                }
            }
            if (is_max) {
                #pragma unroll
                for (int j = 0; j < 16; ++j) {
                    if (kk + j < cnt) {
                        acc.x = fmaxf(acc.x, v[j].x);
                        acc.y = fmaxf(acc.y, v[j].y);
                    }
                }
            } else {
                #pragma unroll
                for (int j = 0; j < 16; ++j) {
                    if (kk + j < cnt) {
                        acc.x += v[j].x;
                        acc.y += v[j].y;
                    }
                }
            }
        }
    }

    if (count == 0) {
        acc = make_float2(0.f, 0.f);             // empty segment -> 0 (any mode)
    } else if (mode == 2) {
        const float c = (float)count;
        acc.x /= c; acc.y /= c;
    }
    st_nt2(out2 + (size_t)g * 64 + lane, acc);
}

// ===========================================================================
// Fallback (atomic path) — only used if ws_size is too small for CSR
// ===========================================================================
__device__ __forceinline__ void atomicMaxFloat(float* addr, float val) {
    if (val >= 0.0f) atomicMax((int*)addr, __float_as_int(val));
    else             atomicMin((unsigned int*)addr, (unsigned int)__float_as_uint(val));
}

__global__ void fb_init_kernel(unsigned int* __restrict__ out, int out_n,
                               float* __restrict__ counts, int nseg,
                               const int* __restrict__ mode_p) {
    const int mode = mode_p[0];
    const unsigned int initv = (mode == 1) ? NEG_INF_BITS : 0u;
    const int stride = gridDim.x * blockDim.x;
    int i = blockIdx.x * blockDim.x + threadIdx.x;
    uint4* out4 = (uint4*)out;
    const int n4 = out_n >> 2;
    uint4 v4 = make_uint4(initv, initv, initv, initv);
    for (int j = i; j < n4; j += stride) out4[j] = v4;
    for (int j = i; j < nseg; j += stride) counts[j] = 0.0f;
}

__global__ void fb_scatter_kernel(const float4* __restrict__ feat4,
                                  const int* __restrict__ inv,
                                  float* __restrict__ out,
                                  float* __restrict__ counts,
                                  int nrows, const int* __restrict__ mode_p) {
    const int mode = mode_p[0];
    const int t = blockIdx.x * blockDim.x + threadIdx.x;
    const int row = t >> 5;
    const int q   = t & 31;
    if (row >= nrows) return;
    const int seg = inv[row];
    const float4 v = feat4[(size_t)row * 32 + q];
    float* dst = out + (size_t)seg * 128 + q * 4;
    if (mode == 1) {
        atomicMaxFloat(dst + 0, v.x); atomicMaxFloat(dst + 1, v.y);
        atomicMaxFloat(dst + 2, v.z); atomicMaxFloat(dst + 3, v.w);
        if (q == 0) atomicAdd(&counts[seg], 1.0f);
    } else {
        atomicAdd(dst + 0, v.x); atomicAdd(dst + 1, v.y);
        atomicAdd(dst + 2, v.z); atomicAdd(dst + 3, v.w);
        if (mode == 2 && q == 0) atomicAdd(&counts[seg], 1.0f);
    }
}

__global__ void fb_fixup_kernel(float* __restrict__ out, int out_n,
                                const float* __restrict__ counts,
                                const int* __restrict__ mode_p) {
    const int mode = mode_p[0];
    if (mode == 3) return;
    const int i = blockIdx.x * blockDim.x + threadIdx.x;
    if (i >= out_n) return;
    const int seg = i >> 7;
    const float c = counts[seg];
    if (mode == 1) { if (c == 0.0f) out[i] = 0.0f; }
    else           { out[i] = out[i] / fmaxf(c, 1.0f); }
}

// ===========================================================================
extern "C" void kernel_launch(void* const* d_in, const int* in_sizes, int n_in,
                              void* d_out, int out_size, void* d_ws, size_t ws_size,
                              hipStream_t stream) {
    const float* feat   = (const float*)d_in[0];
    const int*   inv    = (const int*)d_in[1];
    const int*   mode_p = (const int*)d_in[2];
    float* out = (float*)d_out;

    const int nrows = in_sizes[1];         // 1,000,000
    const int nseg  = out_size / 128;      // 65,536
    const int nblk  = (nseg + SCAN_B - 1) / SCAN_B;   // scan blocks (64)

    // ws layout: counts[nseg] | offsets[nseg+1] | rowidx[nrows] | bsum[nblk] | rank[nrows]
    const size_t need = (size_t)(nseg + (nseg + 1) + nrows + nblk + nrows) * sizeof(int);

    if (ws_size >= need && nblk <= SCAN_B) {
        int* counts  = (int*)d_ws;
        int* offsets = counts + nseg;
        int* rowidx  = offsets + (nseg + 1);
        int* bsum    = rowidx + nrows;
        int* rank    = bsum + nblk;

        // A0) zero counts
        {
            dim3 block(256), grid((nseg + 255) / 256);
            zero_counts_kernel<<<grid, block, 0, stream>>>(counts, nseg);
        }
        // A) histogram + rank
        {
            dim3 block(256), grid(1024);
            hist_rank_kernel<<<grid, block, 0, stream>>>(inv, counts, rank, nrows);
        }
        // B) 3-pass coalesced scan
        scan_reduce_kernel<<<nblk, SCAN_B, 0, stream>>>(counts, bsum, nseg);
        scan_top_kernel<<<1, SCAN_B, 0, stream>>>(bsum, offsets, nblk, nseg);
        scan_down_kernel<<<nblk, SCAN_B, 0, stream>>>(counts, bsum, offsets, nseg);
        // C) scatter row indices (atomic-free)
        {
            dim3 block(256), grid(1024);
            scatteridx_kernel<<<grid, block, 0, stream>>>(inv, rank, offsets, rowidx, nrows);
        }
        // D) gather-reduce (one wave per segment)
        {
            const long long total = (long long)nseg * 64;
            dim3 block(256), grid((unsigned int)((total + 255) / 256));
            seg_reduce_kernel<<<grid, block, 0, stream>>>((const float2*)feat, rowidx,
                                                          offsets, (float2*)out,
                                                          nseg, mode_p);
        }
    } else {
        // fallback: atomic path
        float* counts = (float*)d_ws;
        {
            dim3 block(256), grid(2048);
            fb_init_kernel<<<grid, block, 0, stream>>>((unsigned int*)out, out_size,
                                                       counts, nseg, mode_p);
        }
        {
            const long long total = (long long)nrows * 32;
            dim3 block(256), grid((unsigned int)((total + 255) / 256));
            fb_scatter_kernel<<<grid, block, 0, stream>>>((const float4*)feat, inv,
                                                          out, counts, nrows, mode_p);
        }
        {
            dim3 block(256), grid((out_size + 255) / 256);
            fb_fixup_kernel<<<grid, block, 0, stream>>>(out, out_size, counts, mode_p);
        }
    }
}

// Round 7
// 170.490 us; speedup vs baseline: 1.1924x; 1.1924x over previous
//
#include <hip/hip_runtime.h>
#include <math.h>

#define NEG_INF_BITS 0xFF800000u
#define SCAN_B 1024   // threads per scan block (= tile size)

typedef float f32x4_t __attribute__((ext_vector_type(4)));

__device__ __forceinline__ float4 ld_nt4(const float4* p) {
    f32x4_t v = __builtin_nontemporal_load((const f32x4_t*)p);
    return make_float4(v[0], v[1], v[2], v[3]);
}
__device__ __forceinline__ void st_nt4(float4* p, float4 v) {
    f32x4_t x = {v.x, v.y, v.z, v.w};
    __builtin_nontemporal_store(x, (f32x4_t*)p);
}

// ===========================================================================
// CSR path: zero -> hist+rank -> 3-pass scan -> scatter (no atomics) -> reduce
// ===========================================================================

__global__ void zero_counts_kernel(int* __restrict__ counts, int nseg) {
    const int i = blockIdx.x * blockDim.x + threadIdx.x;
    if (i < nseg) counts[i] = 0;
}

// A) histogram + per-row rank within segment (coalesced rank write)
__global__ void hist_rank_kernel(const int* __restrict__ inv,
                                 int* __restrict__ counts,
                                 int* __restrict__ rank, int n) {
    const int stride = gridDim.x * blockDim.x;
    const int n4 = n >> 2;
    const int4* inv4 = (const int4*)inv;
    int4* rank4 = (int4*)rank;
    for (int i = blockIdx.x * blockDim.x + threadIdx.x; i < n4; i += stride) {
        int4 s = inv4[i];
        int4 rk;
        rk.x = atomicAdd(&counts[s.x], 1);
        rk.y = atomicAdd(&counts[s.y], 1);
        rk.z = atomicAdd(&counts[s.z], 1);
        rk.w = atomicAdd(&counts[s.w], 1);
        rank4[i] = rk;
    }
    if (blockIdx.x == 0 && threadIdx.x < (n & 3)) {
        int i = (n4 << 2) + threadIdx.x;
        rank[i] = atomicAdd(&counts[inv[i]], 1);
    }
}

// B1) per-block reduce of counts tiles -> bsum[block]
__global__ __launch_bounds__(SCAN_B)
void scan_reduce_kernel(const int* __restrict__ counts,
                        int* __restrict__ bsum, int nseg) {
    __shared__ int lds[SCAN_B / 64];
    const int t = threadIdx.x;
    const int idx = blockIdx.x * SCAN_B + t;
    int v = (idx < nseg) ? counts[idx] : 0;
    for (int off = 32; off > 0; off >>= 1) v += __shfl_down(v, off, 64);
    if ((t & 63) == 0) lds[t >> 6] = v;
    __syncthreads();
    if (t < SCAN_B / 64) {
        int s = lds[t];
        for (int off = SCAN_B / 128; off > 0; off >>= 1) s += __shfl_down(s, off, 64);
        if (t == 0) bsum[blockIdx.x] = s;
    }
}

// B2) single small block: exclusive scan of bsum[nblk]; writes offsets[nseg]=total
__global__ __launch_bounds__(SCAN_B)
void scan_top_kernel(int* __restrict__ bsum, int* __restrict__ offsets,
                     int nblk, int nseg) {
    __shared__ int lds[SCAN_B];
    const int t = threadIdx.x;
    int v = (t < nblk) ? bsum[t] : 0;
    lds[t] = v;
    __syncthreads();
    for (int off = 1; off < SCAN_B; off <<= 1) {
        int x = lds[t];
        int add = (t >= off) ? lds[t - off] : 0;
        __syncthreads();
        lds[t] = x + add;
        __syncthreads();
    }
    if (t < nblk) bsum[t] = lds[t] - v;              // exclusive
    if (t == nblk - 1) offsets[nseg] = lds[t];       // total
}

// B3) per-block scan of counts tile + bsum prefix -> offsets
__global__ __launch_bounds__(SCAN_B)
void scan_down_kernel(const int* __restrict__ counts,
                      const int* __restrict__ bsum,
                      int* __restrict__ offsets, int nseg) {
    __shared__ int lds[SCAN_B];
    const int t = threadIdx.x;
    const int idx = blockIdx.x * SCAN_B + t;
    int c = (idx < nseg) ? counts[idx] : 0;
    lds[t] = c;
    __syncthreads();
    for (int off = 1; off < SCAN_B; off <<= 1) {
        int x = lds[t];
        int add = (t >= off) ? lds[t - off] : 0;
        __syncthreads();
        lds[t] = x + add;
        __syncthreads();
    }
    if (idx < nseg) offsets[idx] = bsum[blockIdx.x] + lds[t] - c;  // exclusive
}

// C) scatter row indices into CSR order — NO atomics (uses precomputed rank)
__global__ void scatteridx_kernel(const int* __restrict__ inv,
                                  const int* __restrict__ rank,
                                  const int* __restrict__ offsets,
                                  int* __restrict__ rowidx, int n) {
    const int stride = gridDim.x * blockDim.x;
    const int n4 = n >> 2;
    const int4* inv4 = (const int4*)inv;
    const int4* rank4 = (const int4*)rank;
    for (int i = blockIdx.x * blockDim.x + threadIdx.x; i < n4; i += stride) {
        int4 s  = inv4[i];
        int4 rk = rank4[i];
        int base = i << 2;
        rowidx[offsets[s.x] + rk.x] = base + 0;
        rowidx[offsets[s.y] + rk.y] = base + 1;
        rowidx[offsets[s.z] + rk.z] = base + 2;
        rowidx[offsets[s.w] + rk.w] = base + 3;
    }
    if (blockIdx.x == 0 && threadIdx.x < (n & 3)) {
        int i = (n4 << 2) + threadIdx.x;
        rowidx[offsets[inv[i]] + rank[i]] = i;
    }
}

// D) gather-reduce v3: 32 lanes/segment, float4/lane (as R5), but
//    - uniform PREDICATED batches of 8 (no serial scalar tail)
//    - next batch's rowidx prefetched while current feat gathers in flight
__global__ __launch_bounds__(256)
void seg_reduce_kernel(const float4* __restrict__ feat4,
                       const int* __restrict__ rowidx,
                       const int* __restrict__ offsets,
                       float4* __restrict__ out4,
                       int nseg,
                       const int* __restrict__ mode_p) {
    const int mode = mode_p[0];
    const int t = blockIdx.x * blockDim.x + threadIdx.x;
    const int g = t >> 5;          // segment
    const int q = t & 31;          // float4 column slot
    if (g >= nseg) return;

    const int start = offsets[g];
    const int end   = offsets[g + 1];
    const bool is_max = (mode == 1);

    float4 acc = is_max ? make_float4(-INFINITY, -INFINITY, -INFINITY, -INFINITY)
                        : make_float4(0.f, 0.f, 0.f, 0.f);

    int rows[8];
    #pragma unroll
    for (int k = 0; k < 8; ++k) rows[k] = (start + k < end) ? rowidx[start + k] : -1;

    for (int r = start; r < end; r += 8) {
        // issue feat gathers for the current batch (independent, predicated)
        float4 v[8];
        #pragma unroll
        for (int k = 0; k < 8; ++k) {
            if (rows[k] >= 0) v[k] = ld_nt4(feat4 + (size_t)rows[k] * 32 + q);
        }
        // prefetch next batch's indices (L2 hits) under the feat latency
        int nxt[8];
        const int rn = r + 8;
        #pragma unroll
        for (int k = 0; k < 8; ++k) nxt[k] = (rn + k < end) ? rowidx[rn + k] : -1;
        // accumulate
        if (is_max) {
            #pragma unroll
            for (int k = 0; k < 8; ++k) {
                if (rows[k] >= 0) {
                    acc.x = fmaxf(acc.x, v[k].x);
                    acc.y = fmaxf(acc.y, v[k].y);
                    acc.z = fmaxf(acc.z, v[k].z);
                    acc.w = fmaxf(acc.w, v[k].w);
                }
            }
        } else {
            #pragma unroll
            for (int k = 0; k < 8; ++k) {
                if (rows[k] >= 0) {
                    acc.x += v[k].x; acc.y += v[k].y;
                    acc.z += v[k].z; acc.w += v[k].w;
                }
            }
        }
        #pragma unroll
        for (int k = 0; k < 8; ++k) rows[k] = nxt[k];
    }

    if (end == start) {
        acc = make_float4(0.f, 0.f, 0.f, 0.f);   // empty segment -> 0 (any mode)
    } else if (mode == 2) {
        const float c = (float)(end - start);
        acc.x /= c; acc.y /= c; acc.z /= c; acc.w /= c;
    }
    st_nt4(out4 + (size_t)g * 32 + q, acc);
}

// ===========================================================================
// Fallback (atomic path) — only used if ws_size is too small for CSR
// ===========================================================================
__device__ __forceinline__ void atomicMaxFloat(float* addr, float val) {
    if (val >= 0.0f) atomicMax((int*)addr, __float_as_int(val));
    else             atomicMin((unsigned int*)addr, (unsigned int)__float_as_uint(val));
}

__global__ void fb_init_kernel(unsigned int* __restrict__ out, int out_n,
                               float* __restrict__ counts, int nseg,
                               const int* __restrict__ mode_p) {
    const int mode = mode_p[0];
    const unsigned int initv = (mode == 1) ? NEG_INF_BITS : 0u;
    const int stride = gridDim.x * blockDim.x;
    int i = blockIdx.x * blockDim.x + threadIdx.x;
    uint4* out4 = (uint4*)out;
    const int n4 = out_n >> 2;
    uint4 v4 = make_uint4(initv, initv, initv, initv);
    for (int j = i; j < n4; j += stride) out4[j] = v4;
    for (int j = i; j < nseg; j += stride) counts[j] = 0.0f;
}

__global__ void fb_scatter_kernel(const float4* __restrict__ feat4,
                                  const int* __restrict__ inv,
                                  float* __restrict__ out,
                                  float* __restrict__ counts,
                                  int nrows, const int* __restrict__ mode_p) {
    const int mode = mode_p[0];
    const int t = blockIdx.x * blockDim.x + threadIdx.x;
    const int row = t >> 5;
    const int q   = t & 31;
    if (row >= nrows) return;
    const int seg = inv[row];
    const float4 v = feat4[(size_t)row * 32 + q];
    float* dst = out + (size_t)seg * 128 + q * 4;
    if (mode == 1) {
        atomicMaxFloat(dst + 0, v.x); atomicMaxFloat(dst + 1, v.y);
        atomicMaxFloat(dst + 2, v.z); atomicMaxFloat(dst + 3, v.w);
        if (q == 0) atomicAdd(&counts[seg], 1.0f);
    } else {
        atomicAdd(dst + 0, v.x); atomicAdd(dst + 1, v.y);
        atomicAdd(dst + 2, v.z); atomicAdd(dst + 3, v.w);
        if (mode == 2 && q == 0) atomicAdd(&counts[seg], 1.0f);
    }
}

__global__ void fb_fixup_kernel(float* __restrict__ out, int out_n,
                                const float* __restrict__ counts,
                                const int* __restrict__ mode_p) {
    const int mode = mode_p[0];
    if (mode == 3) return;
    const int i = blockIdx.x * blockDim.x + threadIdx.x;
    if (i >= out_n) return;
    const int seg = i >> 7;
    const float c = counts[seg];
    if (mode == 1) { if (c == 0.0f) out[i] = 0.0f; }
    else           { out[i] = out[i] / fmaxf(c, 1.0f); }
}

// ===========================================================================
extern "C" void kernel_launch(void* const* d_in, const int* in_sizes, int n_in,
                              void* d_out, int out_size, void* d_ws, size_t ws_size,
                              hipStream_t stream) {
    const float* feat   = (const float*)d_in[0];
    const int*   inv    = (const int*)d_in[1];
    const int*   mode_p = (const int*)d_in[2];
    float* out = (float*)d_out;

    const int nrows = in_sizes[1];         // 1,000,000
    const int nseg  = out_size / 128;      // 65,536
    const int nblk  = (nseg + SCAN_B - 1) / SCAN_B;   // scan blocks (64)

    // ws layout: counts[nseg] | offsets[nseg+1] | rowidx[nrows] | bsum[nblk] | rank[nrows]
    const size_t need = (size_t)(nseg + (nseg + 1) + nrows + nblk + nrows) * sizeof(int);

    if (ws_size >= need && nblk <= SCAN_B) {
        int* counts  = (int*)d_ws;
        int* offsets = counts + nseg;
        int* rowidx  = offsets + (nseg + 1);
        int* bsum    = rowidx + nrows;
        int* rank    = bsum + nblk;

        // A0) zero counts
        {
            dim3 block(256), grid((nseg + 255) / 256);
            zero_counts_kernel<<<grid, block, 0, stream>>>(counts, nseg);
        }
        // A) histogram + rank
        {
            dim3 block(256), grid(1024);
            hist_rank_kernel<<<grid, block, 0, stream>>>(inv, counts, rank, nrows);
        }
        // B) 3-pass coalesced scan
        scan_reduce_kernel<<<nblk, SCAN_B, 0, stream>>>(counts, bsum, nseg);
        scan_top_kernel<<<1, SCAN_B, 0, stream>>>(bsum, offsets, nblk, nseg);
        scan_down_kernel<<<nblk, SCAN_B, 0, stream>>>(counts, bsum, offsets, nseg);
        // C) scatter row indices (atomic-free)
        {
            dim3 block(256), grid(1024);
            scatteridx_kernel<<<grid, block, 0, stream>>>(inv, rank, offsets, rowidx, nrows);
        }
        // D) gather-reduce (32 lanes/segment, pipelined predicated batches)
        {
            const long long total = (long long)nseg * 32;
            dim3 block(256), grid((unsigned int)((total + 255) / 256));
            seg_reduce_kernel<<<grid, block, 0, stream>>>((const float4*)feat, rowidx,
                                                          offsets, (float4*)out,
                                                          nseg, mode_p);
        }
    } else {
        // fallback: atomic path
        float* counts = (float*)d_ws;
        {
            dim3 block(256), grid(2048);
            fb_init_kernel<<<grid, block, 0, stream>>>((unsigned int*)out, out_size,
                                                       counts, nseg, mode_p);
        }
        {
            const long long total = (long long)nrows * 32;
            dim3 block(256), grid((unsigned int)((total + 255) / 256));
            fb_scatter_kernel<<<grid, block, 0, stream>>>((const float4*)feat, inv,
                                                          out, counts, nrows, mode_p);
        }
        {
            dim3 block(256), grid((out_size + 255) / 256);
            fb_fixup_kernel<<<grid, block, 0, stream>>>(out, out_size, counts, mode_p);
        }
    }
}